// Round 1
// baseline (11454.512 us; speedup 1.0000x reference)
//
#include <hip/hip_runtime.h>

#define BATCH 512
#define D_IN  2048
#define D_MCB 16000
#define N_OUT 3000

typedef __bf16 bf16x8 __attribute__((ext_vector_type(8)));
typedef float  f32x4  __attribute__((ext_vector_type(4)));

// ---------------------------------------------------------------------------
// Kernel 1: fused count-sketch + circular convolution (sparse pair expansion).
// One block per batch row. z[b,:] accumulated in LDS via ds_add_f32 atomics.
//   z[b, (h1[i]+h2[j]) % 16000] += (s1[i]*x0[b,i]) * (s2[j]*x1[b,j])
// Output written as bf16 into workspace (feeds the MFMA GEMM).
// LDS: 64000 (z) + 16384 (a2/h2 packed for single b64 broadcast) = 80384 B
//      -> 2 blocks/CU.
// ---------------------------------------------------------------------------
__global__ __launch_bounds__(256) void mcb_conv_kernel(
    const float* __restrict__ x0, const float* __restrict__ x1,
    const float* __restrict__ s1, const float* __restrict__ s2,
    const int* __restrict__ h1, const int* __restrict__ h2,
    __bf16* __restrict__ zb)
{
    __shared__ float  zs[D_MCB];      // 64000 B accumulation buffer
    __shared__ float2 jdata[D_IN];    // 16384 B: .x = s2*x1, .y = h2 bits

    const int b = blockIdx.x;
    const int t = threadIdx.x;

    for (int k = t; k < D_MCB; k += 256) zs[k] = 0.0f;
    for (int j = t; j < D_IN; j += 256) {
        float a = s2[j] * x1[b * D_IN + j];
        jdata[j] = make_float2(a, __int_as_float(h2[j]));
    }

    // Each thread owns 8 i's (registers), coalesced load pattern.
    float a1r[8];
    int   h1r[8];
#pragma unroll
    for (int r = 0; r < 8; ++r) {
        int i = t + 256 * r;
        a1r[r] = s1[i] * x0[b * D_IN + i];
        h1r[r] = h1[i];
    }
    __syncthreads();

    for (int j = 0; j < D_IN; ++j) {
        float2 jd = jdata[j];          // one ds_read_b64 broadcast per j
        float a2j = jd.x;
        int   h2j = __float_as_int(jd.y);
#pragma unroll
        for (int r = 0; r < 8; ++r) {
            int idx = h1r[r] + h2j;    // < 32000, single conditional wrap
            if (idx >= D_MCB) idx -= D_MCB;
            atomicAdd(&zs[idx], a1r[r] * a2j);
        }
    }
    __syncthreads();

    for (int k = t; k < D_MCB; k += 256) {
        zb[b * D_MCB + k] = (__bf16)zs[k];
    }
}

// ---------------------------------------------------------------------------
// Kernel 2: out = relu(z @ W^T + bias), bf16 MFMA 16x16x32.
// A = z_bf16 [512, 16000] K-major; B = W [3000, 16000] K-major (fp32,
// converted to bf16 in-register). Wave tile 32x32 (2x2 frags), block 64x64.
// Fragment maps (HW-verified, learn_hip m89/m91):
//   A: m = lane&15, k = (lane>>4)*8 + j     (8 contiguous bf16 = 16 B/lane)
//   B: n = lane&15, k = (lane>>4)*8 + j
//   D: col = lane&15, row = (lane>>4)*4 + reg
// ---------------------------------------------------------------------------
__global__ __launch_bounds__(256) void mcb_gemm_kernel(
    const __bf16* __restrict__ zb, const float* __restrict__ W,
    const float* __restrict__ bias, float* __restrict__ out)
{
    const int lane = threadIdx.x & 63;
    const int wave = threadIdx.x >> 6;
    const int wm = wave >> 1;
    const int wn = wave & 1;
    const int llo = lane & 15;
    const int lhi = lane >> 4;

    const int m0 = blockIdx.y * 64 + wm * 32;   // M tiles: 8
    const int n0 = blockIdx.x * 64 + wn * 32;   // N tiles: 47 (3008, guarded)

    f32x4 acc[2][2] = {};

    const int arow0 = m0 + llo;
    const int bcol0 = n0 + llo;
    const int kk = lhi * 8;

    const __bf16* aptr0 = zb + (size_t)arow0 * D_MCB + kk;
    const __bf16* aptr1 = aptr0 + (size_t)16 * D_MCB;
    const float*  bptr0 = W + (size_t)bcol0 * D_MCB + kk;
    const float*  bptr1 = bptr0 + (size_t)16 * D_MCB;
    const bool bok0 = (bcol0 < N_OUT);
    const bool bok1 = (bcol0 + 16 < N_OUT);

    for (int k = 0; k < D_MCB; k += 32) {
        bf16x8 a0 = *(const bf16x8*)(aptr0 + k);
        bf16x8 a1 = *(const bf16x8*)(aptr1 + k);

        bf16x8 b0 = {}, b1 = {};
        if (bok0) {
            f32x4 w0 = *(const f32x4*)(bptr0 + k);
            f32x4 w1 = *(const f32x4*)(bptr0 + k + 4);
#pragma unroll
            for (int q = 0; q < 4; ++q) { b0[q] = (__bf16)w0[q]; b0[q + 4] = (__bf16)w1[q]; }
        }
        if (bok1) {
            f32x4 w0 = *(const f32x4*)(bptr1 + k);
            f32x4 w1 = *(const f32x4*)(bptr1 + k + 4);
#pragma unroll
            for (int q = 0; q < 4; ++q) { b1[q] = (__bf16)w0[q]; b1[q + 4] = (__bf16)w1[q]; }
        }

        acc[0][0] = __builtin_amdgcn_mfma_f32_16x16x32_bf16(a0, b0, acc[0][0], 0, 0, 0);
        acc[0][1] = __builtin_amdgcn_mfma_f32_16x16x32_bf16(a0, b1, acc[0][1], 0, 0, 0);
        acc[1][0] = __builtin_amdgcn_mfma_f32_16x16x32_bf16(a1, b0, acc[1][0], 0, 0, 0);
        acc[1][1] = __builtin_amdgcn_mfma_f32_16x16x32_bf16(a1, b1, acc[1][1], 0, 0, 0);
    }

#pragma unroll
    for (int bn = 0; bn < 2; ++bn) {
        int col = bcol0 + bn * 16;
        if (col >= N_OUT) continue;
        float bv = bias[col];
#pragma unroll
        for (int am = 0; am < 2; ++am) {
            int rbase = m0 + am * 16 + lhi * 4;
#pragma unroll
            for (int r = 0; r < 4; ++r) {
                float v = acc[am][bn][r] + bv;
                out[(size_t)(rbase + r) * N_OUT + col] = v > 0.0f ? v : 0.0f;
            }
        }
    }
}

extern "C" void kernel_launch(void* const* d_in, const int* in_sizes, int n_in,
                              void* d_out, int out_size, void* d_ws, size_t ws_size,
                              hipStream_t stream) {
    // setup_inputs() order: x0, x1, s1, s2, W, b, h1, h2
    const float* x0   = (const float*)d_in[0];
    const float* x1   = (const float*)d_in[1];
    const float* s1   = (const float*)d_in[2];
    const float* s2   = (const float*)d_in[3];
    const float* W    = (const float*)d_in[4];
    const float* bias = (const float*)d_in[5];
    const int*   h1   = (const int*)d_in[6];
    const int*   h2   = (const int*)d_in[7];
    float* out = (float*)d_out;

    __bf16* zb = (__bf16*)d_ws;   // 512*16000*2 = 16.4 MB scratch

    mcb_conv_kernel<<<BATCH, 256, 0, stream>>>(x0, x1, s1, s2, h1, h2, zb);
    mcb_gemm_kernel<<<dim3(47, 8), 256, 0, stream>>>(zb, W, bias, out);
}

// Round 2
// 11266.982 us; speedup vs baseline: 1.0166x; 1.0166x over previous
//
#include <hip/hip_runtime.h>
#include <stdint.h>

#define BATCH 512
#define D_IN  2048
#define D_MCB 16000
#define N_OUT 3000

typedef __bf16 bf16x8 __attribute__((ext_vector_type(8)));
typedef __bf16 bf16x4 __attribute__((ext_vector_type(4)));
typedef float  f32x4  __attribute__((ext_vector_type(4)));

// Native LDS float atomic add, no return value -> no lgkmcnt dependency.
// addr is a 32-bit LDS byte address (flat->local addrspacecast == truncate).
__device__ __forceinline__ void lds_fadd(unsigned addr, float v) {
    asm volatile("ds_add_f32 %0, %1" :: "v"(addr), "v"(v) : "memory");
}

// ---------------------------------------------------------------------------
// Kernel 1: fused count-sketch + circular convolution (sparse pair expansion).
// One block per batch row; z[b,:] accumulated in LDS via native ds_add_f32.
//   z[b, (h1[i]+h2[j]) % 16000] += (s1[i]*x0[b,i]) * (s2[j]*x1[b,j])
// ---------------------------------------------------------------------------
__global__ __launch_bounds__(256) void mcb_conv_kernel(
    const float* __restrict__ x0, const float* __restrict__ x1,
    const float* __restrict__ s1, const float* __restrict__ s2,
    const int* __restrict__ h1, const int* __restrict__ h2,
    __bf16* __restrict__ zb)
{
    __shared__ float  zs[D_MCB];      // 64000 B accumulation buffer
    __shared__ float2 jdata[D_IN];    // 16384 B: .x = s2*x1, .y = 4*h2 bits

    const int b = blockIdx.x;
    const int t = threadIdx.x;

    for (int k = t; k < D_MCB; k += 256) zs[k] = 0.0f;
    for (int j = t; j < D_IN; j += 256) {
        float a = s2[j] * x1[b * D_IN + j];
        jdata[j] = make_float2(a, __int_as_float(h2[j] * 4));
    }

    const unsigned zbase = (unsigned)(uint64_t)(uintptr_t)&zs[0];

    // Each thread owns 8 i's (registers), coalesced load pattern.
    float    a1r[8];
    unsigned h1off[8];                // 4*h1[i] (byte offset, un-based)
#pragma unroll
    for (int r = 0; r < 8; ++r) {
        int i = t + 256 * r;
        a1r[r]   = s1[i] * x0[b * D_IN + i];
        h1off[r] = 4u * (unsigned)h1[i];
    }
    __syncthreads();

    float2 jd = jdata[0];
    for (int j = 0; j < D_IN; ++j) {
        float    a2j  = jd.x;
        unsigned h2j4 = (unsigned)__float_as_int(jd.y);
        jd = jdata[(j + 1) & (D_IN - 1)];      // prefetch (broadcast read)
#pragma unroll
        for (int r = 0; r < 8; ++r) {
            unsigned off  = h1off[r] + h2j4;           // < 127996
            unsigned offw = off - 4u * D_MCB;          // underflows if < 64000
            unsigned sel  = off < offw ? off : offw;   // v_min_u32 == mod
            lds_fadd(zbase + sel, a1r[r] * a2j);
        }
    }
    __syncthreads();

    for (int k = t; k < D_MCB; k += 256) {
        zb[(size_t)b * D_MCB + k] = (__bf16)zs[k];
    }
}

// ---------------------------------------------------------------------------
// Kernel 1.5: W fp32 -> bf16 pre-convert (one pass, ~290 MB of HBM traffic).
// ---------------------------------------------------------------------------
__global__ __launch_bounds__(256) void wconv_kernel(
    const float* __restrict__ W, __bf16* __restrict__ Wb)
{
    size_t i = ((size_t)blockIdx.x * 256 + threadIdx.x) * 4;
    f32x4 w = *(const f32x4*)(W + i);
    bf16x4 o;
#pragma unroll
    for (int q = 0; q < 4; ++q) o[q] = (__bf16)w[q];
    *(bf16x4*)(Wb + i) = o;
}

// ---------------------------------------------------------------------------
// Kernel 2 (fast path): out = relu(z @ Wb^T + bias), bf16 MFMA 16x16x32.
// A = z_bf16 [512,16000] K-major; B = Wb [3000,16000] K-major bf16.
// Wave tile 32x32 (2x2 frags), block 64x64.
// Fragment maps (HW-verified):
//   A/B: m/n = lane&15, k = (lane>>4)*8 + j ; D: col=lane&15, row=(lane>>4)*4+reg
// ---------------------------------------------------------------------------
__global__ __launch_bounds__(256) void mcb_gemm_bf16_kernel(
    const __bf16* __restrict__ zbm, const __bf16* __restrict__ Wb,
    const float* __restrict__ bias, float* __restrict__ out)
{
    const int lane = threadIdx.x & 63;
    const int wave = threadIdx.x >> 6;
    const int wm = wave >> 1;
    const int wn = wave & 1;
    const int llo = lane & 15;
    const int lhi = lane >> 4;

    const int m0 = blockIdx.y * 64 + wm * 32;
    const int n0 = blockIdx.x * 64 + wn * 32;

    f32x4 acc[2][2] = {};

    const int arow0 = m0 + llo;
    const int bcol0 = n0 + llo;
    const int kk = lhi * 8;

    const __bf16* aptr0 = zbm + (size_t)arow0 * D_MCB + kk;
    const __bf16* aptr1 = aptr0 + (size_t)16 * D_MCB;
    const __bf16* bptr0 = Wb + (size_t)bcol0 * D_MCB + kk;
    const __bf16* bptr1 = bptr0 + (size_t)16 * D_MCB;
    const bool bok0 = (bcol0 < N_OUT);
    const bool bok1 = (bcol0 + 16 < N_OUT);

    for (int k = 0; k < D_MCB; k += 32) {
        bf16x8 a0 = *(const bf16x8*)(aptr0 + k);
        bf16x8 a1 = *(const bf16x8*)(aptr1 + k);
        bf16x8 b0 = {}, b1 = {};
        if (bok0) b0 = *(const bf16x8*)(bptr0 + k);
        if (bok1) b1 = *(const bf16x8*)(bptr1 + k);

        acc[0][0] = __builtin_amdgcn_mfma_f32_16x16x32_bf16(a0, b0, acc[0][0], 0, 0, 0);
        acc[0][1] = __builtin_amdgcn_mfma_f32_16x16x32_bf16(a0, b1, acc[0][1], 0, 0, 0);
        acc[1][0] = __builtin_amdgcn_mfma_f32_16x16x32_bf16(a1, b0, acc[1][0], 0, 0, 0);
        acc[1][1] = __builtin_amdgcn_mfma_f32_16x16x32_bf16(a1, b1, acc[1][1], 0, 0, 0);
    }

#pragma unroll
    for (int bn = 0; bn < 2; ++bn) {
        int col = bcol0 + bn * 16;
        if (col >= N_OUT) continue;
        float bv = bias[col];
#pragma unroll
        for (int am = 0; am < 2; ++am) {
            int rbase = m0 + am * 16 + lhi * 4;
#pragma unroll
            for (int r = 0; r < 4; ++r) {
                float v = acc[am][bn][r] + bv;
                out[(size_t)(rbase + r) * N_OUT + col] = v > 0.0f ? v : 0.0f;
            }
        }
    }
}

// ---------------------------------------------------------------------------
// Kernel 2 (fallback): same GEMM but W stays fp32, converted in-register.
// Used only if d_ws is too small for the bf16 W copy. (Proven in round 1.)
// ---------------------------------------------------------------------------
__global__ __launch_bounds__(256) void mcb_gemm_f32_kernel(
    const __bf16* __restrict__ zbm, const float* __restrict__ W,
    const float* __restrict__ bias, float* __restrict__ out)
{
    const int lane = threadIdx.x & 63;
    const int wave = threadIdx.x >> 6;
    const int wm = wave >> 1;
    const int wn = wave & 1;
    const int llo = lane & 15;
    const int lhi = lane >> 4;

    const int m0 = blockIdx.y * 64 + wm * 32;
    const int n0 = blockIdx.x * 64 + wn * 32;

    f32x4 acc[2][2] = {};

    const int arow0 = m0 + llo;
    const int bcol0 = n0 + llo;
    const int kk = lhi * 8;

    const __bf16* aptr0 = zbm + (size_t)arow0 * D_MCB + kk;
    const __bf16* aptr1 = aptr0 + (size_t)16 * D_MCB;
    const float*  bptr0 = W + (size_t)bcol0 * D_MCB + kk;
    const float*  bptr1 = bptr0 + (size_t)16 * D_MCB;
    const bool bok0 = (bcol0 < N_OUT);
    const bool bok1 = (bcol0 + 16 < N_OUT);

    for (int k = 0; k < D_MCB; k += 32) {
        bf16x8 a0 = *(const bf16x8*)(aptr0 + k);
        bf16x8 a1 = *(const bf16x8*)(aptr1 + k);

        bf16x8 b0 = {}, b1 = {};
        if (bok0) {
            f32x4 w0 = *(const f32x4*)(bptr0 + k);
            f32x4 w1 = *(const f32x4*)(bptr0 + k + 4);
#pragma unroll
            for (int q = 0; q < 4; ++q) { b0[q] = (__bf16)w0[q]; b0[q + 4] = (__bf16)w1[q]; }
        }
        if (bok1) {
            f32x4 w0 = *(const f32x4*)(bptr1 + k);
            f32x4 w1 = *(const f32x4*)(bptr1 + k + 4);
#pragma unroll
            for (int q = 0; q < 4; ++q) { b1[q] = (__bf16)w0[q]; b1[q + 4] = (__bf16)w1[q]; }
        }

        acc[0][0] = __builtin_amdgcn_mfma_f32_16x16x32_bf16(a0, b0, acc[0][0], 0, 0, 0);
        acc[0][1] = __builtin_amdgcn_mfma_f32_16x16x32_bf16(a0, b1, acc[0][1], 0, 0, 0);
        acc[1][0] = __builtin_amdgcn_mfma_f32_16x16x32_bf16(a1, b0, acc[1][0], 0, 0, 0);
        acc[1][1] = __builtin_amdgcn_mfma_f32_16x16x32_bf16(a1, b1, acc[1][1], 0, 0, 0);
    }

#pragma unroll
    for (int bn = 0; bn < 2; ++bn) {
        int col = bcol0 + bn * 16;
        if (col >= N_OUT) continue;
        float bv = bias[col];
#pragma unroll
        for (int am = 0; am < 2; ++am) {
            int rbase = m0 + am * 16 + lhi * 4;
#pragma unroll
            for (int r = 0; r < 4; ++r) {
                float v = acc[am][bn][r] + bv;
                out[(size_t)(rbase + r) * N_OUT + col] = v > 0.0f ? v : 0.0f;
            }
        }
    }
}

extern "C" void kernel_launch(void* const* d_in, const int* in_sizes, int n_in,
                              void* d_out, int out_size, void* d_ws, size_t ws_size,
                              hipStream_t stream) {
    // setup_inputs() order: x0, x1, s1, s2, W, b, h1, h2
    const float* x0   = (const float*)d_in[0];
    const float* x1   = (const float*)d_in[1];
    const float* s1   = (const float*)d_in[2];
    const float* s2   = (const float*)d_in[3];
    const float* W    = (const float*)d_in[4];
    const float* bias = (const float*)d_in[5];
    const int*   h1   = (const int*)d_in[6];
    const int*   h2   = (const int*)d_in[7];
    float* out = (float*)d_out;

    const size_t zb_bytes = (size_t)BATCH * D_MCB * sizeof(__bf16);   // 16,384,000
    const size_t wb_bytes = (size_t)N_OUT * D_MCB * sizeof(__bf16);   // 96,000,000

    __bf16* zbm = (__bf16*)d_ws;

    mcb_conv_kernel<<<BATCH, 256, 0, stream>>>(x0, x1, s1, s2, h1, h2, zbm);

    if (ws_size >= zb_bytes + wb_bytes) {
        __bf16* Wb = (__bf16*)((char*)d_ws + zb_bytes);  // 16B-aligned offset
        // 48,000,000 elems / 4 per thread / 256 per block = 46875 blocks
        wconv_kernel<<<46875, 256, 0, stream>>>(W, Wb);
        mcb_gemm_bf16_kernel<<<dim3(47, 8), 256, 0, stream>>>(zbm, Wb, bias, out);
    } else {
        mcb_gemm_f32_kernel<<<dim3(47, 8), 256, 0, stream>>>(zbm, W, bias, out);
    }
}

// Round 3
// 2539.220 us; speedup vs baseline: 4.5110x; 4.4372x over previous
//
#include <hip/hip_runtime.h>
#include <stdint.h>

#define BATCH 512
#define D_IN  2048
#define D_MCB 16000
#define N_OUT 3000

typedef __bf16 bf16x8 __attribute__((ext_vector_type(8)));
typedef __bf16 bf16x4 __attribute__((ext_vector_type(4)));
typedef float  f32x4  __attribute__((ext_vector_type(4)));

// Native LDS float atomic add (fire-and-forget). addr = 32-bit LDS byte addr.
__device__ __forceinline__ void lds_fadd(unsigned addr, float v) {
    asm volatile("ds_add_f32 %0, %1" :: "v"(addr), "v"(v) : "memory");
}

// ---------------------------------------------------------------------------
// Kernel 1: count-sketch + circular convolution, GATHER formulation.
//   z[b,k] = sum_i a1[b,i] * p2[b, (k - h1[i]) mod d],  a1 = s1*x0
//   p2[b,r] = sum_{j: h2[j]=r} s2[j]*x1[b,j]   (built by tiny atomic scatter)
// p2x = p2 replicated over ~2 periods in LDS (no mod in hot loop), stored
// XOR-swizzled at 16B-chunk granularity: phys_chunk = c ^ ((c>>4)&7), so the
// per-i 17 aligned ds_read_b128 (contiguous 68-float window per lane) spread
// across all bank columns. delta = shift&3 is wave-uniform -> 4 static FMA
// wirings. Wave w owns k in [4000w, 4000w+4096), overlap masked at store.
// LDS: 131072 (p2x) + 16384 (idata) = 147456 B -> 1 block/CU, 4 waves.
// Measured lesson (R1/R2): ds_add_f32 wave-op ~194 cyc flat -> atomics in the
// pair loop are hopeless; gather is LDS-read-BW bound instead (~10x better).
// ---------------------------------------------------------------------------
__global__ __launch_bounds__(256, 1) void mcb_conv_kernel(
    const float* __restrict__ x0, const float* __restrict__ x1,
    const float* __restrict__ s1, const float* __restrict__ s2,
    const int* __restrict__ h1, const int* __restrict__ h2,
    __bf16* __restrict__ zb)
{
    __shared__ f32x4  p2x4[8192];     // 131072 B, swizzled, covers r in [0,32768)
    __shared__ float2 idata[D_IN];    // 16384 B: (a1[i], bitcast shift s_i)

    const int b    = blockIdx.x;
    const int t    = threadIdx.x;
    const int lane = t & 63;
    const int wave = t >> 6;

    // --- zero p2x (bijective swizzle => plain linear zeroing is fine) ---
    f32x4 z4 = {0.f, 0.f, 0.f, 0.f};
    for (int c = t; c < 8192; c += 256) p2x4[c] = z4;

    // --- stage i-data: a1[i] = s1[i]*x0[b,i], shift s_i = d - h1[i] in [1,d] ---
    for (int i = t; i < D_IN; i += 256) {
        float a1 = s1[i] * x0[b * D_IN + i];
        int   s  = D_MCB - h1[i];
        idata[i] = make_float2(a1, __int_as_float(s));
    }
    __syncthreads();

    // --- scatter p2 into swizzled p2x, 3 periods bounded by 32768 floats ---
    const unsigned p2base = (unsigned)(uintptr_t)&p2x4[0];
    for (int j = t; j < D_IN; j += 256) {
        float a2 = s2[j] * x1[b * D_IN + j];
        int   r  = h2[j];
#pragma unroll
        for (int p = 0; p < 3; ++p) {
            int rr = r + p * D_MCB;
            if (rr < 32768) {
                int c  = rr >> 2;
                int pc = c ^ ((c >> 4) & 7);
                lds_fadd(p2base + (unsigned)(pc * 16 + (rr & 3) * 4), a2);
            }
        }
    }
    __syncthreads();

    // --- gather main loop: lane owns k in [k0, k0+64) ---
    const int wbase = wave * 4000;
    const int k0    = wbase + lane * 64;

    float zacc[64];
#pragma unroll
    for (int q = 0; q < 64; ++q) zacc[q] = 0.f;

#define FMABLOCK(D)                                                        \
    {                                                                      \
        _Pragma("unroll")                                                  \
        for (int q = 0; q < 64; ++q)                                       \
            zacc[q] += a1 * w[(q + (D)) >> 2][(q + (D)) & 3];              \
    }

    float2 jd = idata[0];
#pragma unroll 2
    for (int i = 0; i < D_IN; ++i) {
        float a1 = jd.x;
        int   s  = __float_as_int(jd.y);
        jd = idata[(i + 1) & (D_IN - 1)];          // broadcast prefetch

        const int c0    = (k0 >> 2) + (s >> 2);    // aligned chunk base
        const int delta = s & 3;

        f32x4 w[17];
#pragma unroll
        for (int tt = 0; tt < 17; ++tt) {
            int c = c0 + tt;
            w[tt] = p2x4[c ^ ((c >> 4) & 7)];      // conflict-free b128
        }

        if      (delta == 0) FMABLOCK(0)
        else if (delta == 1) FMABLOCK(1)
        else if (delta == 2) FMABLOCK(2)
        else                 FMABLOCK(3)
    }
#undef FMABLOCK

    // --- store bf16 z, masking the 96-float slice overlap (all bounds %8==0) ---
    const int klim = wbase + 4000;                 // wave3: 16000 exactly
#pragma unroll
    for (int g = 0; g < 8; ++g) {
        int kg = k0 + g * 8;
        if (kg < klim) {
            bf16x8 o;
#pragma unroll
            for (int e = 0; e < 8; ++e) o[e] = (__bf16)zacc[g * 8 + e];
            *(bf16x8*)(zb + (size_t)b * D_MCB + kg) = o;
        }
    }
}

// ---------------------------------------------------------------------------
// Kernel 1.5: W fp32 -> bf16 pre-convert (one pass).
// ---------------------------------------------------------------------------
__global__ __launch_bounds__(256) void wconv_kernel(
    const float* __restrict__ W, __bf16* __restrict__ Wb)
{
    size_t i = ((size_t)blockIdx.x * 256 + threadIdx.x) * 4;
    f32x4 w = *(const f32x4*)(W + i);
    bf16x4 o;
#pragma unroll
    for (int q = 0; q < 4; ++q) o[q] = (__bf16)w[q];
    *(bf16x4*)(Wb + i) = o;
}

// ---------------------------------------------------------------------------
// Kernel 2 (fast path): out = relu(z @ Wb^T + bias), bf16 MFMA 16x16x32.
// ---------------------------------------------------------------------------
__global__ __launch_bounds__(256) void mcb_gemm_bf16_kernel(
    const __bf16* __restrict__ zbm, const __bf16* __restrict__ Wb,
    const float* __restrict__ bias, float* __restrict__ out)
{
    const int lane = threadIdx.x & 63;
    const int wave = threadIdx.x >> 6;
    const int wm = wave >> 1;
    const int wn = wave & 1;
    const int llo = lane & 15;
    const int lhi = lane >> 4;

    const int m0 = blockIdx.y * 64 + wm * 32;
    const int n0 = blockIdx.x * 64 + wn * 32;

    f32x4 acc[2][2] = {};

    const int arow0 = m0 + llo;
    const int bcol0 = n0 + llo;
    const int kk = lhi * 8;

    const __bf16* aptr0 = zbm + (size_t)arow0 * D_MCB + kk;
    const __bf16* aptr1 = aptr0 + (size_t)16 * D_MCB;
    const __bf16* bptr0 = Wb + (size_t)bcol0 * D_MCB + kk;
    const __bf16* bptr1 = bptr0 + (size_t)16 * D_MCB;
    const bool bok0 = (bcol0 < N_OUT);
    const bool bok1 = (bcol0 + 16 < N_OUT);

    for (int k = 0; k < D_MCB; k += 32) {
        bf16x8 a0 = *(const bf16x8*)(aptr0 + k);
        bf16x8 a1 = *(const bf16x8*)(aptr1 + k);
        bf16x8 b0 = {}, b1 = {};
        if (bok0) b0 = *(const bf16x8*)(bptr0 + k);
        if (bok1) b1 = *(const bf16x8*)(bptr1 + k);

        acc[0][0] = __builtin_amdgcn_mfma_f32_16x16x32_bf16(a0, b0, acc[0][0], 0, 0, 0);
        acc[0][1] = __builtin_amdgcn_mfma_f32_16x16x32_bf16(a0, b1, acc[0][1], 0, 0, 0);
        acc[1][0] = __builtin_amdgcn_mfma_f32_16x16x32_bf16(a1, b0, acc[1][0], 0, 0, 0);
        acc[1][1] = __builtin_amdgcn_mfma_f32_16x16x32_bf16(a1, b1, acc[1][1], 0, 0, 0);
    }

#pragma unroll
    for (int bn = 0; bn < 2; ++bn) {
        int col = bcol0 + bn * 16;
        if (col >= N_OUT) continue;
        float bv = bias[col];
#pragma unroll
        for (int am = 0; am < 2; ++am) {
            int rbase = m0 + am * 16 + lhi * 4;
#pragma unroll
            for (int r = 0; r < 4; ++r) {
                float v = acc[am][bn][r] + bv;
                out[(size_t)(rbase + r) * N_OUT + col] = v > 0.0f ? v : 0.0f;
            }
        }
    }
}

// ---------------------------------------------------------------------------
// Kernel 2 (fallback): W stays fp32, converted in-register.
// ---------------------------------------------------------------------------
__global__ __launch_bounds__(256) void mcb_gemm_f32_kernel(
    const __bf16* __restrict__ zbm, const float* __restrict__ W,
    const float* __restrict__ bias, float* __restrict__ out)
{
    const int lane = threadIdx.x & 63;
    const int wave = threadIdx.x >> 6;
    const int wm = wave >> 1;
    const int wn = wave & 1;
    const int llo = lane & 15;
    const int lhi = lane >> 4;

    const int m0 = blockIdx.y * 64 + wm * 32;
    const int n0 = blockIdx.x * 64 + wn * 32;

    f32x4 acc[2][2] = {};

    const int arow0 = m0 + llo;
    const int bcol0 = n0 + llo;
    const int kk = lhi * 8;

    const __bf16* aptr0 = zbm + (size_t)arow0 * D_MCB + kk;
    const __bf16* aptr1 = aptr0 + (size_t)16 * D_MCB;
    const float*  bptr0 = W + (size_t)bcol0 * D_MCB + kk;
    const float*  bptr1 = bptr0 + (size_t)16 * D_MCB;
    const bool bok0 = (bcol0 < N_OUT);
    const bool bok1 = (bcol0 + 16 < N_OUT);

    for (int k = 0; k < D_MCB; k += 32) {
        bf16x8 a0 = *(const bf16x8*)(aptr0 + k);
        bf16x8 a1 = *(const bf16x8*)(aptr1 + k);

        bf16x8 b0 = {}, b1 = {};
        if (bok0) {
            f32x4 w0 = *(const f32x4*)(bptr0 + k);
            f32x4 w1 = *(const f32x4*)(bptr0 + k + 4);
#pragma unroll
            for (int q = 0; q < 4; ++q) { b0[q] = (__bf16)w0[q]; b0[q + 4] = (__bf16)w1[q]; }
        }
        if (bok1) {
            f32x4 w0 = *(const f32x4*)(bptr1 + k);
            f32x4 w1 = *(const f32x4*)(bptr1 + k + 4);
#pragma unroll
            for (int q = 0; q < 4; ++q) { b1[q] = (__bf16)w0[q]; b1[q + 4] = (__bf16)w1[q]; }
        }

        acc[0][0] = __builtin_amdgcn_mfma_f32_16x16x32_bf16(a0, b0, acc[0][0], 0, 0, 0);
        acc[0][1] = __builtin_amdgcn_mfma_f32_16x16x32_bf16(a0, b1, acc[0][1], 0, 0, 0);
        acc[1][0] = __builtin_amdgcn_mfma_f32_16x16x32_bf16(a1, b0, acc[1][0], 0, 0, 0);
        acc[1][1] = __builtin_amdgcn_mfma_f32_16x16x32_bf16(a1, b1, acc[1][1], 0, 0, 0);
    }

#pragma unroll
    for (int bn = 0; bn < 2; ++bn) {
        int col = bcol0 + bn * 16;
        if (col >= N_OUT) continue;
        float bv = bias[col];
#pragma unroll
        for (int am = 0; am < 2; ++am) {
            int rbase = m0 + am * 16 + lhi * 4;
#pragma unroll
            for (int r = 0; r < 4; ++r) {
                float v = acc[am][bn][r] + bv;
                out[(size_t)(rbase + r) * N_OUT + col] = v > 0.0f ? v : 0.0f;
            }
        }
    }
}

extern "C" void kernel_launch(void* const* d_in, const int* in_sizes, int n_in,
                              void* d_out, int out_size, void* d_ws, size_t ws_size,
                              hipStream_t stream) {
    // setup_inputs() order: x0, x1, s1, s2, W, b, h1, h2
    const float* x0   = (const float*)d_in[0];
    const float* x1   = (const float*)d_in[1];
    const float* s1   = (const float*)d_in[2];
    const float* s2   = (const float*)d_in[3];
    const float* W    = (const float*)d_in[4];
    const float* bias = (const float*)d_in[5];
    const int*   h1   = (const int*)d_in[6];
    const int*   h2   = (const int*)d_in[7];
    float* out = (float*)d_out;

    const size_t zb_bytes = (size_t)BATCH * D_MCB * sizeof(__bf16);   // 16,384,000
    const size_t wb_bytes = (size_t)N_OUT * D_MCB * sizeof(__bf16);   // 96,000,000

    __bf16* zbm = (__bf16*)d_ws;

    mcb_conv_kernel<<<BATCH, 256, 0, stream>>>(x0, x1, s1, s2, h1, h2, zbm);

    if (ws_size >= zb_bytes + wb_bytes) {
        __bf16* Wb = (__bf16*)((char*)d_ws + zb_bytes);
        wconv_kernel<<<46875, 256, 0, stream>>>(W, Wb);
        mcb_gemm_bf16_kernel<<<dim3(47, 8), 256, 0, stream>>>(zbm, Wb, bias, out);
    } else {
        mcb_gemm_f32_kernel<<<dim3(47, 8), 256, 0, stream>>>(zbm, W, bias, out);
    }
}

// Round 4
// 2182.383 us; speedup vs baseline: 5.2486x; 1.1635x over previous
//
#include <hip/hip_runtime.h>
#include <stdint.h>

#define BATCH 512
#define D_IN  2048
#define D_MCB 16000
#define N_OUT 3000

typedef __bf16 bf16x8 __attribute__((ext_vector_type(8)));
typedef __bf16 bf16x4 __attribute__((ext_vector_type(4)));
typedef float  f32x4  __attribute__((ext_vector_type(4)));

// Native LDS float atomic add (fire-and-forget). addr = 32-bit LDS byte addr.
__device__ __forceinline__ void lds_fadd(unsigned addr, float v) {
    asm volatile("ds_add_f32 %0, %1" :: "v"(addr), "v"(v) : "memory");
}

// ---------------------------------------------------------------------------
// Kernel 1: count-sketch + circular convolution, GATHER with bf16 p2 table.
//   z[b,k] = sum_i a1[b,i] * p2[b, (k + s_i) mod d],  s_i = d - h1[i]
// R3 lesson: fp32 gather is LDS-BW bound (4.25 B/FMA, 17 b128/i, 1.97 ms).
// Fix: p2 table in bf16 -> 9 b128/i (2.25 B/FMA), unpack = 1 VALU (<<16,
// exact). LDS = 64 KB p2x(bf16, ~2 periods, XOR-swizzled) + 16 KB idata
// = exactly 80 KB -> 2 blocks/CU (occupancy 2x, 512 blocks in one round).
// Build: fp32 p2 via ds_add_f32 into an overlay region, then register-staged
// barrier-separated convert to swizzled bf16 (no ds_pk_add dependency).
// delta = s&7 is wave-uniform -> 8 static FMA wirings.
// ---------------------------------------------------------------------------
__global__ __launch_bounds__(256, 2) void mcb_conv_kernel(
    const float* __restrict__ x0, const float* __restrict__ x1,
    const float* __restrict__ s1, const float* __restrict__ s2,
    const int* __restrict__ h1, const int* __restrict__ h2,
    __bf16* __restrict__ zb)
{
    __shared__ __align__(16) char smem[81920];
    unsigned short* p2x  = (unsigned short*)smem;          // [32768] bf16 bits
    float*          p2f  = (float*)smem;                   // [16000] fp32 overlay
    float2*         idata = (float2*)(smem + 65536);       // [2048] (a1, s bits)

    const int b    = blockIdx.x;
    const int t    = threadIdx.x;
    const int lane = t & 63;
    const int wave = t >> 6;

    // --- phase 1: zero fp32 p2, stage idata ---
    for (int k = t; k < D_MCB; k += 256) p2f[k] = 0.0f;
    for (int i = t; i < D_IN; i += 256) {
        float a1 = s1[i] * x0[b * D_IN + i];
        int   s  = D_MCB - h1[i];                 // in [1, 16000]
        idata[i] = make_float2(a1, __int_as_float(s));
    }
    __syncthreads();

    // --- phase 2: scatter p2 (fp32, plain layout, tiny: 2048 atomics) ---
    for (int j = t; j < D_IN; j += 256) {
        float a2 = s2[j] * x1[b * D_IN + j];
        unsigned addr = (unsigned)(uintptr_t)&p2f[h2[j]];
        lds_fadd(addr, a2);
    }
    __syncthreads();

    // --- phase 3: convert fp32 p2 -> bf16 p2x, replicated to 32768 elems,
    //     XOR-swizzled at 8-elem (16 B) chunks: phys = c ^ ((c>>3)&7).
    //     Register-staged: read all sources, barrier, write (overlay-safe). ---
    bf16x8 stage[16];
#pragma unroll
    for (int m = 0; m < 16; ++m) {
        int c  = t + 256 * m;                     // chunk in [0,4096)
        int e8 = c << 3;                          // elem base, [0,32768)
        if (e8 >= 2 * D_MCB) e8 -= 2 * D_MCB;
        else if (e8 >= D_MCB) e8 -= D_MCB;
        f32x4 lo = *(const f32x4*)(p2f + e8);
        f32x4 hi = *(const f32x4*)(p2f + e8 + 4);
        bf16x8 o;
#pragma unroll
        for (int q = 0; q < 4; ++q) { o[q] = (__bf16)lo[q]; o[q + 4] = (__bf16)hi[q]; }
        stage[m] = o;
    }
    __syncthreads();
#pragma unroll
    for (int m = 0; m < 16; ++m) {
        int c  = t + 256 * m;
        int pc = c ^ ((c >> 3) & 7);
        *(bf16x8*)(p2x + pc * 8) = stage[m];
    }
    __syncthreads();

    // --- phase 4: gather. Lane owns k in [k0, k0+64), wave w covers
    //     [4000w, 4000w+4096) (96-elem overlap masked at store). ---
    const int k0 = wave * 4000 + (lane << 6);     // multiple of 8
    const int K8 = k0 >> 3;

    float zacc[64];
#pragma unroll
    for (int q = 0; q < 64; ++q) zacc[q] = 0.f;

    // w: 9 chunks = 36 dwords; elem e=q+D: dword e>>1, half e&1.
    // bf16->f32: lo half = bits<<16, hi half = bits & 0xffff0000 (both exact).
#define FMAB(D)                                                           \
    {                                                                     \
        const unsigned* wd = (const unsigned*)w;                          \
        _Pragma("unroll")                                                 \
        for (int q = 0; q < 64; ++q) {                                    \
            const int e = q + (D);                                        \
            unsigned dwv  = wd[e >> 1];                                   \
            unsigned bits = (e & 1) ? (dwv & 0xffff0000u) : (dwv << 16);  \
            zacc[q] += a1 * __uint_as_float(bits);                        \
        }                                                                 \
    }

    float2 jd = idata[0];
    for (int i = 0; i < D_IN; ++i) {
        float a1 = jd.x;
        int   s  = __float_as_int(jd.y);
        jd = idata[(i + 1) & (D_IN - 1)];          // broadcast prefetch

        const int c0 = K8 + (s >> 3);              // window chunk base
        const int dl = s & 7;                      // wave-uniform delta

        uint4 w[9];
#pragma unroll
        for (int tt = 0; tt < 9; ++tt) {
            int c = c0 + tt;
            w[tt] = *(const uint4*)(p2x + (c ^ ((c >> 3) & 7)) * 8);
        }

        switch (dl) {
            case 0: FMAB(0) break;
            case 1: FMAB(1) break;
            case 2: FMAB(2) break;
            case 3: FMAB(3) break;
            case 4: FMAB(4) break;
            case 5: FMAB(5) break;
            case 6: FMAB(6) break;
            default: FMAB(7) break;
        }
    }
#undef FMAB

    // --- store bf16 z, masking wave overlap (all bounds % 8 == 0) ---
    const int klim = wave * 4000 + 4000;
#pragma unroll
    for (int g = 0; g < 8; ++g) {
        int kg = k0 + g * 8;
        if (kg < klim) {
            bf16x8 o;
#pragma unroll
            for (int e = 0; e < 8; ++e) o[e] = (__bf16)zacc[g * 8 + e];
            *(bf16x8*)(zb + (size_t)b * D_MCB + kg) = o;
        }
    }
}

// ---------------------------------------------------------------------------
// Kernel 1.5: W fp32 -> bf16 pre-convert (one pass).
// ---------------------------------------------------------------------------
__global__ __launch_bounds__(256) void wconv_kernel(
    const float* __restrict__ W, __bf16* __restrict__ Wb)
{
    size_t i = ((size_t)blockIdx.x * 256 + threadIdx.x) * 4;
    f32x4 w = *(const f32x4*)(W + i);
    bf16x4 o;
#pragma unroll
    for (int q = 0; q < 4; ++q) o[q] = (__bf16)w[q];
    *(bf16x4*)(Wb + i) = o;
}

// ---------------------------------------------------------------------------
// Kernel 2 (fast path): out = relu(z @ Wb^T + bias), bf16 MFMA 16x16x32.
// ---------------------------------------------------------------------------
__global__ __launch_bounds__(256) void mcb_gemm_bf16_kernel(
    const __bf16* __restrict__ zbm, const __bf16* __restrict__ Wb,
    const float* __restrict__ bias, float* __restrict__ out)
{
    const int lane = threadIdx.x & 63;
    const int wave = threadIdx.x >> 6;
    const int wm = wave >> 1;
    const int wn = wave & 1;
    const int llo = lane & 15;
    const int lhi = lane >> 4;

    const int m0 = blockIdx.y * 64 + wm * 32;
    const int n0 = blockIdx.x * 64 + wn * 32;

    f32x4 acc[2][2] = {};

    const int arow0 = m0 + llo;
    const int bcol0 = n0 + llo;
    const int kk = lhi * 8;

    const __bf16* aptr0 = zbm + (size_t)arow0 * D_MCB + kk;
    const __bf16* aptr1 = aptr0 + (size_t)16 * D_MCB;
    const __bf16* bptr0 = Wb + (size_t)bcol0 * D_MCB + kk;
    const __bf16* bptr1 = bptr0 + (size_t)16 * D_MCB;
    const bool bok0 = (bcol0 < N_OUT);
    const bool bok1 = (bcol0 + 16 < N_OUT);

    for (int k = 0; k < D_MCB; k += 32) {
        bf16x8 a0 = *(const bf16x8*)(aptr0 + k);
        bf16x8 a1 = *(const bf16x8*)(aptr1 + k);
        bf16x8 b0 = {}, b1 = {};
        if (bok0) b0 = *(const bf16x8*)(bptr0 + k);
        if (bok1) b1 = *(const bf16x8*)(bptr1 + k);

        acc[0][0] = __builtin_amdgcn_mfma_f32_16x16x32_bf16(a0, b0, acc[0][0], 0, 0, 0);
        acc[0][1] = __builtin_amdgcn_mfma_f32_16x16x32_bf16(a0, b1, acc[0][1], 0, 0, 0);
        acc[1][0] = __builtin_amdgcn_mfma_f32_16x16x32_bf16(a1, b0, acc[1][0], 0, 0, 0);
        acc[1][1] = __builtin_amdgcn_mfma_f32_16x16x32_bf16(a1, b1, acc[1][1], 0, 0, 0);
    }

#pragma unroll
    for (int bn = 0; bn < 2; ++bn) {
        int col = bcol0 + bn * 16;
        if (col >= N_OUT) continue;
        float bv = bias[col];
#pragma unroll
        for (int am = 0; am < 2; ++am) {
            int rbase = m0 + am * 16 + lhi * 4;
#pragma unroll
            for (int r = 0; r < 4; ++r) {
                float v = acc[am][bn][r] + bv;
                out[(size_t)(rbase + r) * N_OUT + col] = v > 0.0f ? v : 0.0f;
            }
        }
    }
}

// ---------------------------------------------------------------------------
// Kernel 2 (fallback): W stays fp32, converted in-register.
// ---------------------------------------------------------------------------
__global__ __launch_bounds__(256) void mcb_gemm_f32_kernel(
    const __bf16* __restrict__ zbm, const float* __restrict__ W,
    const float* __restrict__ bias, float* __restrict__ out)
{
    const int lane = threadIdx.x & 63;
    const int wave = threadIdx.x >> 6;
    const int wm = wave >> 1;
    const int wn = wave & 1;
    const int llo = lane & 15;
    const int lhi = lane >> 4;

    const int m0 = blockIdx.y * 64 + wm * 32;
    const int n0 = blockIdx.x * 64 + wn * 32;

    f32x4 acc[2][2] = {};

    const int arow0 = m0 + llo;
    const int bcol0 = n0 + llo;
    const int kk = lhi * 8;

    const __bf16* aptr0 = zbm + (size_t)arow0 * D_MCB + kk;
    const __bf16* aptr1 = aptr0 + (size_t)16 * D_MCB;
    const float*  bptr0 = W + (size_t)bcol0 * D_MCB + kk;
    const float*  bptr1 = bptr0 + (size_t)16 * D_MCB;
    const bool bok0 = (bcol0 < N_OUT);
    const bool bok1 = (bcol0 + 16 < N_OUT);

    for (int k = 0; k < D_MCB; k += 32) {
        bf16x8 a0 = *(const bf16x8*)(aptr0 + k);
        bf16x8 a1 = *(const bf16x8*)(aptr1 + k);

        bf16x8 b0 = {}, b1 = {};
        if (bok0) {
            f32x4 w0 = *(const f32x4*)(bptr0 + k);
            f32x4 w1 = *(const f32x4*)(bptr0 + k + 4);
#pragma unroll
            for (int q = 0; q < 4; ++q) { b0[q] = (__bf16)w0[q]; b0[q + 4] = (__bf16)w1[q]; }
        }
        if (bok1) {
            f32x4 w0 = *(const f32x4*)(bptr1 + k);
            f32x4 w1 = *(const f32x4*)(bptr1 + k + 4);
#pragma unroll
            for (int q = 0; q < 4; ++q) { b1[q] = (__bf16)w0[q]; b1[q + 4] = (__bf16)w1[q]; }
        }

        acc[0][0] = __builtin_amdgcn_mfma_f32_16x16x32_bf16(a0, b0, acc[0][0], 0, 0, 0);
        acc[0][1] = __builtin_amdgcn_mfma_f32_16x16x32_bf16(a0, b1, acc[0][1], 0, 0, 0);
        acc[1][0] = __builtin_amdgcn_mfma_f32_16x16x32_bf16(a1, b0, acc[1][0], 0, 0, 0);
        acc[1][1] = __builtin_amdgcn_mfma_f32_16x16x32_bf16(a1, b1, acc[1][1], 0, 0, 0);
    }

#pragma unroll
    for (int bn = 0; bn < 2; ++bn) {
        int col = bcol0 + bn * 16;
        if (col >= N_OUT) continue;
        float bv = bias[col];
#pragma unroll
        for (int am = 0; am < 2; ++am) {
            int rbase = m0 + am * 16 + lhi * 4;
#pragma unroll
            for (int r = 0; r < 4; ++r) {
                float v = acc[am][bn][r] + bv;
                out[(size_t)(rbase + r) * N_OUT + col] = v > 0.0f ? v : 0.0f;
            }
        }
    }
}

extern "C" void kernel_launch(void* const* d_in, const int* in_sizes, int n_in,
                              void* d_out, int out_size, void* d_ws, size_t ws_size,
                              hipStream_t stream) {
    // setup_inputs() order: x0, x1, s1, s2, W, b, h1, h2
    const float* x0   = (const float*)d_in[0];
    const float* x1   = (const float*)d_in[1];
    const float* s1   = (const float*)d_in[2];
    const float* s2   = (const float*)d_in[3];
    const float* W    = (const float*)d_in[4];
    const float* bias = (const float*)d_in[5];
    const int*   h1   = (const int*)d_in[6];
    const int*   h2   = (const int*)d_in[7];
    float* out = (float*)d_out;

    const size_t zb_bytes = (size_t)BATCH * D_MCB * sizeof(__bf16);   // 16,384,000
    const size_t wb_bytes = (size_t)N_OUT * D_MCB * sizeof(__bf16);   // 96,000,000

    __bf16* zbm = (__bf16*)d_ws;

    mcb_conv_kernel<<<BATCH, 256, 0, stream>>>(x0, x1, s1, s2, h1, h2, zbm);

    if (ws_size >= zb_bytes + wb_bytes) {
        __bf16* Wb = (__bf16*)((char*)d_ws + zb_bytes);
        wconv_kernel<<<46875, 256, 0, stream>>>(W, Wb);
        mcb_gemm_bf16_kernel<<<dim3(47, 8), 256, 0, stream>>>(zbm, Wb, bias, out);
    } else {
        mcb_gemm_f32_kernel<<<dim3(47, 8), 256, 0, stream>>>(zbm, W, bias, out);
    }
}